// Round 15
// baseline (462.500 us; speedup 1.0000x reference)
//
#include <hip/hip_runtime.h>
#include <math.h>

#define T_SEQ 4096
#define HD 128
#define NH 4
#define DS 512
#define SCALE 0.08838834764831845f
#define NEG9 (-1.0e9f)
#define BN 32
#define VT_STRIDE 4096
#define NCH 128        // T_SEQ / BN
#define NRT 256        // T_SEQ / 16
#define SEGC 16        // chunks per j-segment
#define NPART_H 1152   // sum over rt of ns(rt) = rt/32+1
#define ALIVE_MIN (-999999936.0f)  // smallest fp32 score an alive row can have

typedef __attribute__((ext_vector_type(8))) _Float16 half8;
typedef __attribute__((ext_vector_type(4))) float floatx4;

__device__ __forceinline__ float sigmoidf_(float x) {
  if (x >= 0.0f) return 1.0f / (1.0f + expf(-x));
  float e = expf(x);
  return e / (1.0f + e);
}

// ---------------- prep: K h+e cvt, V transpose, V sums ----------------
__global__ __launch_bounds__(256) void prep_kernel(
    const float* __restrict__ K, const float* __restrict__ V,
    _Float16* __restrict__ Kh, _Float16* __restrict__ Ke,
    _Float16* __restrict__ Vt, float* __restrict__ Vpart) {
  const int bx = blockIdx.x, tid = threadIdx.x;
  __shared__ float tile[32][33];
  __shared__ float red[2][128];
  if (bx < 1024) {  // fp32 -> fp16 h+e split for K
    int idx = (bx * 256 + tid) * 8;
    float4 a = *(const float4*)&K[idx];
    float4 b = *(const float4*)&K[idx + 4];
    float v[8] = {a.x, a.y, a.z, a.w, b.x, b.y, b.z, b.w};
    half8 oh, oe;
#pragma unroll
    for (int t = 0; t < 8; ++t) {
      _Float16 hh = (_Float16)v[t];
      oh[t] = hh;
      oe[t] = (_Float16)(v[t] - (float)hh);
    }
    *(half8*)&Kh[idx] = oh;
    *(half8*)&Ke[idx] = oe;
  } else if (bx < 3072) {  // V transpose -> Vt fp16
    int b = bx - 1024;
    int jt = b & 127, dt = (b >> 7) & 3, h = b >> 9;
    int tx = tid & 31, ty = tid >> 5;
    for (int k = 0; k < 4; ++k) {
      int row = jt * 32 + ty + k * 8;
      tile[ty + k * 8][tx] = V[((h * T_SEQ) + row) * HD + dt * 32 + tx];
    }
    __syncthreads();
    for (int k = 0; k < 4; ++k) {
      int d = dt * 32 + ty + k * 8;
      int j = jt * 32 + tx;
      Vt[((size_t)(h * HD) + d) * VT_STRIDE + j] = (_Float16)tile[tx][ty + k * 8];
    }
  } else {  // V column partial sums
    int b = bx - 3072;
    int h = b >> 2, part = b & 3;
    int d = tid & 127, hlf = tid >> 7;
    float s = 0.f;
    for (int j = part * 1024 + hlf; j < part * 1024 + 1024; j += 2)
      s += V[(size_t)((h * T_SEQ) + j) * HD + d];
    red[hlf][d] = s;
    __syncthreads();
    if (tid < 128)
      Vpart[(h * 4 + part) * 128 + tid] = red[0][tid] + red[1][tid];
  }
}

// ---------------- Kernel A: downsampled scores (fp32, bit-stable) ----------------
__global__ __launch_bounds__(256) void sds_kernel(const float* __restrict__ Q,
                                                  const float* __restrict__ K,
                                                  float* __restrict__ sds) {
  __shared__ float Qs[16][132];
  __shared__ float Ks[16][132];
  const int h = blockIdx.z;
  const int by = blockIdx.y, bx = blockIdx.x;
  const int tid = threadIdx.y * 16 + threadIdx.x;
  for (int t = tid; t < 512; t += 256) {
    int r = t >> 5, f = (t & 31) * 4;
    *(float4*)&Qs[r][f] = *(const float4*)&Q[((h * T_SEQ) + (by * 16 + r) * 8) * HD + f];
    *(float4*)&Ks[r][f] = *(const float4*)&K[((h * T_SEQ) + (bx * 16 + r) * 8) * HD + f];
  }
  __syncthreads();
  const int ty = threadIdx.y, tx = threadIdx.x;
  float acc = 0.0f;
  for (int k = 0; k < 32; ++k) {
    float4 a = *(float4*)&Qs[ty][k * 4];
    float4 b = *(float4*)&Ks[tx][k * 4];
    acc += a.x * b.x + a.y * b.y + a.z * b.z + a.w * b.w;
  }
  sds[((h * DS) + by * 16 + ty) * DS + bx * 16 + tx] = acc * SCALE;
}

// ---------------- Kernel B: fused exact 128th-largest (waves 0/1) + bias max ----------------
__global__ __launch_bounds__(256) void bmaxthr_kernel(const float* __restrict__ sds,
                                                      const float* __restrict__ U,
                                                      float* __restrict__ thrG,
                                                      float* __restrict__ bmax16) {
  const int h = blockIdx.y, rt = blockIdx.x;
  const int tid = threadIdx.x, ww = tid >> 6, lane = tid & 63;
  __shared__ float thrS[2];
  if (ww < 2) {  // radix select for ds-rows 2rt, 2rt+1 (bit-identical sequence)
    const int row = h * DS + rt * 2 + ww;
    unsigned v[8];
    for (int t = 0; t < 8; ++t) {
      float f = sds[(size_t)row * DS + t * 64 + lane];
      unsigned b = __float_as_uint(f);
      v[t] = (b & 0x80000000u) ? ~b : (b | 0x80000000u);
    }
    unsigned prefix = 0u;
    for (int bit = 31; bit >= 0; --bit) {
      unsigned cand = prefix | (1u << bit);
      int c = 0;
      for (int t = 0; t < 8; ++t) c += (v[t] >= cand) ? 1 : 0;
      for (int off = 32; off > 0; off >>= 1) c += __shfl_down(c, off, 64);
      c = __shfl(c, 0, 64);
      if (c >= 128) prefix = cand;
    }
    if (lane == 0) {
      unsigned b = (prefix & 0x80000000u) ? (prefix ^ 0x80000000u) : ~prefix;
      float t = __uint_as_float(b);
      thrS[ww] = t;
      thrG[row] = t;
    }
  }
  __syncthreads();
  // bias-max phase (bit-identical bias sequence)
  const int r = lane >> 2, q = lane & 3;
  const int i = rt * 16 + r;
  float u = U[i];
  u = fminf(fmaxf(u, 0.0f), 1.0f);
  const float us = 1.0f + u;
  const int idl = r >> 3;
  const float bb = us * thrS[idl];
  const float* srow = &sds[((h * DS) + rt * 2 + idl) * DS];
  for (int c = ww; c < NCH; c += 4) {
    float sval = srow[(c << 2) + q];
    float a = us * sval;
    float bias = (1.0f - sigmoidf_((a - bb) * 10.0f)) * NEG9;
    for (int off = 1; off < 64; off <<= 1)
      bias = fmaxf(bias, __shfl_xor(bias, off, 64));
    if (lane == 0) bmax16[((h * NRT) + rt) * NCH + c] = bias;
  }
}

// ---------------- Kernel C: split-j MFMA flash attention, paired-chunk visits ----------------
__global__ __launch_bounds__(256) void attn14_kernel(
    const float* __restrict__ Qf, const _Float16* __restrict__ Kh,
    const _Float16* __restrict__ Ke, const _Float16* __restrict__ Vt,
    const float* __restrict__ U, const float* __restrict__ sds,
    const float* __restrict__ thrG, const float* __restrict__ bmax16,
    float* __restrict__ Pm, float* __restrict__ Pl, _Float16* __restrict__ Po,
    const float* __restrict__ Vpart, float* __restrict__ out) {
  const int h = blockIdx.y;
  const int p = NPART_H - 1 - (int)blockIdx.x;  // heavy tiles (large rt) first
  int a = 0;
  while (a < 7 && p >= 16 * (a + 1) * (a + 2)) ++a;
  const int ns = a + 1;
  const int off = p - 16 * a * (a + 1);
  const int q_ = off / ns;
  const int rt = 32 * a + q_;
  const int seg = off - q_ * ns;
  const int i0 = rt * 16;
  const int nchunks = (rt >> 1) + 1;
  const int c0 = seg * SEGC;
  const int len = min(SEGC, nchunks - c0);  // >= 1

  const int tid = threadIdx.x;
  const int w = tid >> 6;
  const int lane = tid & 63;
  const int quad = lane >> 4;
  const int n = lane & 15;

  // Obuf's per-wave 8KB slice doubles as that wave's 64-wide P staging (2KB):
  // Ps is used only inside the chunk loop, Obuf only after it; regions are
  // per-wave disjoint, so no cross-wave hazard.
  __shared__ float Obuf[4][16][128];
  __shared__ float mW[4][16], lW[4][16], esW[4][16];
  __shared__ float Mrow[16], Lrow[16], LinvS[16], VsS[128];
  __shared__ int deadS[16];
  _Float16* PsW = (_Float16*)&Obuf[w][0][0];  // [16][64] halfs

  // per-row constants (rows quad*4+r); 4 rows of a quad share one ds-row
  const int myid = (i0 >> 3) + (quad >> 1);
  float us[4], bb[4];
  for (int r = 0; r < 4; ++r) {
    int i = i0 + quad * 4 + r;
    float u = U[i];
    u = fminf(fmaxf(u, 0.0f), 1.0f);
    us[r] = 1.0f + u;
    bb[r] = us[r] * thrG[h * DS + myid];
  }

  // Q A-fragments: in-kernel h+e split (bit-identical; validated R9-R14)
  half8 qfh[4], qfe[4];
  {
    const float* qrow = &Qf[(size_t)((h * T_SEQ) + i0 + n) * HD + quad * 8];
#pragma unroll
    for (int d = 0; d < 4; ++d) {
      float4 x0 = *(const float4*)&qrow[d * 32];
      float4 x1 = *(const float4*)&qrow[d * 32 + 4];
      float v[8] = {x0.x, x0.y, x0.z, x0.w, x1.x, x1.y, x1.z, x1.w};
      half8 hh, ee;
#pragma unroll
      for (int t = 0; t < 8; ++t) {
        _Float16 hv = (_Float16)v[t];
        hh[t] = hv;
        ee[t] = (_Float16)(v[t] - (float)hv);
      }
      qfh[d] = hh;
      qfe[d] = ee;
    }
  }

  floatx4 acc[8];
  for (int t = 0; t < 8; ++t) acc[t] = (floatx4){0.f, 0.f, 0.f, 0.f};
  float m_[4], l_[4];
  for (int r = 0; r < 4; ++r) { m_[r] = -INFINITY; l_[r] = 0.0f; }

  // ---- pair planning: wave w owns pairs pp = w + 4k (chunks c0+2pp, c0+2pp+1) ----
  const int nPairs = (len + 1) >> 1;  // <= 8
  const int nMineP = (nPairs > w) ? ((nPairs - w + 3) >> 2) : 0;  // <= 2
  float bvalP = -3.0e38f;
  if (lane < nMineP) {
    const int pp = w + (lane << 2);
    const float* bm = &bmax16[((h * NRT) + rt) * NCH + c0 + (pp << 1)];
    float b0 = bm[0];
    float b1 = ((pp << 1) + 1 < len) ? bm[1] : NEG9;
    // encode: value = max (for hot/cold checks); null iff both exactly NEG9
    bvalP = fmaxf(b0, b1);
    if (b0 == NEG9 && b1 == NEG9) bvalP = NEG9;  // max==NEG9 anyway; explicit
  }
  const unsigned bits = (nMineP > 0) ? ((1u << nMineP) - 1u) : 0u;
  const unsigned hotMask = (unsigned)__ballot(lane < nMineP && bvalP > -124.0f) & bits;
  const unsigned nullMask = (unsigned)__ballot(lane < nMineP && bvalP == NEG9) & bits;
  const unsigned coldMask = bits & ~hotMask & ~nullMask;
  // null pairs: every score exactly -1e9f; alive-row weight <= e^-64 (ref too);
  // fully-dead rows resolved exactly at merge via uniform-softmax closed form.

  for (int sweep = 0; sweep < 2; ++sweep) {
    unsigned mask = (sweep == 0) ? hotMask : coldMask;
    while (mask) {
      const int cc = __builtin_ctz(mask);
      mask &= mask - 1u;
      if (sweep == 1) {
        float bm16 = __shfl(bvalP, cc, 64);
        float mm = fminf(fminf(m_[0], m_[1]), fminf(m_[2], m_[3]));
        mm = fminf(mm, __shfl_xor(mm, 16, 64));
        mm = fminf(mm, __shfl_xor(mm, 32, 64));
        if (bm16 + 12.0f < mm - 40.0f) continue;  // contribution < e^-40 relative
      }
      const int pp = w + (cc << 2);
      const int cA = c0 + (pp << 1);
      const bool haveB = ((pp << 1) + 1 < len);
      const int j0 = cA * BN;  // pair spans [j0, j0+64) when haveB

      // ---- sds loads + one sigmoid per lane per chunk (bit-identical values) ----
      const int br = n & 3;
      const int bjd = n >> 2;
      const float svA = sds[((h * DS) + myid) * DS + (cA << 2) + bjd];
      float svB = 0.0f;
      if (haveB) svB = sds[((h * DS) + myid) * DS + (cA << 2) + 4 + bjd];

      // ---- K loads chunk A ----
      const size_t kbaseA = (size_t)((h * T_SEQ) + j0 + n) * HD + quad * 8;
      half8 kh0[4], kh1[4], ke0[4], ke1[4];
#pragma unroll
      for (int d = 0; d < 4; ++d) {
        kh0[d] = *(const half8*)&Kh[kbaseA + d * 32];
        kh1[d] = *(const half8*)&Kh[kbaseA + 16 * HD + d * 32];
        ke0[d] = *(const half8*)&Ke[kbaseA + d * 32];
        ke1[d] = *(const half8*)&Ke[kbaseA + 16 * HD + d * 32];
      }

      // ---- bias sigmoids + gathers (overlap K latency) ----
      const float aaA = us[br] * svA;
      const float myBiasA = (1.0f - sigmoidf_((aaA - bb[br]) * 10.0f)) * NEG9;
      float myBiasB = 0.0f;
      if (haveB) {
        const float aaB = us[br] * svB;
        myBiasB = (1.0f - sigmoidf_((aaB - bb[br]) * 10.0f)) * NEG9;
      }
      float biasA0[4], biasA1[4], biasB0[4], biasB1[4];
      {
        const int baseLane = (quad << 4) + ((n >> 3) << 2);
#pragma unroll
        for (int r = 0; r < 4; ++r) {
          biasA0[r] = __shfl(myBiasA, baseLane + r, 64);
          biasA1[r] = __shfl(myBiasA, baseLane + 8 + r, 64);
          biasB0[r] = __shfl(myBiasB, baseLane + r, 64);
          biasB1[r] = __shfl(myBiasB, baseLane + 8 + r, 64);
        }
      }

      // ---- QK^T chunk A: 3-term split, 24 mfma, split accumulators ----
      floatx4 S0a = (floatx4){0.f, 0.f, 0.f, 0.f};
      floatx4 S0b = (floatx4){0.f, 0.f, 0.f, 0.f};
      floatx4 S1a = (floatx4){0.f, 0.f, 0.f, 0.f};
      floatx4 S1b = (floatx4){0.f, 0.f, 0.f, 0.f};
#pragma unroll
      for (int d = 0; d < 2; ++d) {
        S0a = __builtin_amdgcn_mfma_f32_16x16x32_f16(qfh[d], kh0[d], S0a, 0, 0, 0);
        S0b = __builtin_amdgcn_mfma_f32_16x16x32_f16(qfh[d + 2], kh0[d + 2], S0b, 0, 0, 0);
        S1a = __builtin_amdgcn_mfma_f32_16x16x32_f16(qfh[d], kh1[d], S1a, 0, 0, 0);
        S1b = __builtin_amdgcn_mfma_f32_16x16x32_f16(qfh[d + 2], kh1[d + 2], S1b, 0, 0, 0);
      }
#pragma unroll
      for (int d = 0; d < 2; ++d) {
        S0a = __builtin_amdgcn_mfma_f32_16x16x32_f16(qfe[d], kh0[d], S0a, 0, 0, 0);
        S0b = __builtin_amdgcn_mfma_f32_16x16x32_f16(qfe[d + 2], kh0[d + 2], S0b, 0, 0, 0);
        S1a = __builtin_amdgcn_mfma_f32_16x16x32_f16(qfe[d], kh1[d], S1a, 0, 0, 0);
        S1b = __builtin_amdgcn_mfma_f32_16x16x32_f16(qfe[d + 2], kh1[d + 2], S1b, 0, 0, 0);
        S0a = __builtin_amdgcn_mfma_f32_16x16x32_f16(qfh[d], ke0[d], S0a, 0, 0, 0);
        S0b = __builtin_amdgcn_mfma_f32_16x16x32_f16(qfh[d + 2], ke0[d + 2], S0b, 0, 0, 0);
        S1a = __builtin_amdgcn_mfma_f32_16x16x32_f16(qfh[d], ke1[d], S1a, 0, 0, 0);
        S1b = __builtin_amdgcn_mfma_f32_16x16x32_f16(qfh[d + 2], ke1[d + 2], S1b, 0, 0, 0);
      }
      const floatx4 S0 = S0a + S0b;
      const floatx4 S1 = S1a + S1b;

      // ---- QK^T chunk B (reuses K registers) ----
      floatx4 S2 = (floatx4){0.f, 0.f, 0.f, 0.f};
      floatx4 S3 = (floatx4){0.f, 0.f, 0.f, 0.f};
      if (haveB) {
        const size_t kbaseB = kbaseA + 32 * HD;
#pragma unroll
        for (int d = 0; d < 4; ++d) {
          kh0[d] = *(const half8*)&Kh[kbaseB + d * 32];
          kh1[d] = *(const half8*)&Kh[kbaseB + 16 * HD + d * 32];
          ke0[d] = *(const half8*)&Ke[kbaseB + d * 32];
          ke1[d] = *(const half8*)&Ke[kbaseB + 16 * HD + d * 32];
        }
        floatx4 S2a = (floatx4){0.f, 0.f, 0.f, 0.f};
        floatx4 S2b = (floatx4){0.f, 0.f, 0.f, 0.f};
        floatx4 S3a = (floatx4){0.f, 0.f, 0.f, 0.f};
        floatx4 S3b = (floatx4){0.f, 0.f, 0.f, 0.f};
#pragma unroll
        for (int d = 0; d < 2; ++d) {
          S2a = __builtin_amdgcn_mfma_f32_16x16x32_f16(qfh[d], kh0[d], S2a, 0, 0, 0);
          S2b = __builtin_amdgcn_mfma_f32_16x16x32_f16(qfh[d + 2], kh0[d + 2], S2b, 0, 0, 0);
          S3a = __builtin_amdgcn_mfma_f32_16x16x32_f16(qfh[d], kh1[d], S3a, 0, 0, 0);
          S3b = __builtin_amdgcn_mfma_f32_16x16x32_f16(qfh[d + 2], kh1[d + 2], S3b, 0, 0, 0);
        }
#pragma unroll
        for (int d = 0; d < 2; ++d) {
          S2a = __builtin_amdgcn_mfma_f32_16x16x32_f16(qfe[d], kh0[d], S2a, 0, 0, 0);
          S2b = __builtin_amdgcn_mfma_f32_16x16x32_f16(qfe[d + 2], kh0[d + 2], S2b, 0, 0, 0);
          S3a = __builtin_amdgcn_mfma_f32_16x16x32_f16(qfe[d], kh1[d], S3a, 0, 0, 0);
          S3b = __builtin_amdgcn_mfma_f32_16x16x32_f16(qfe[d + 2], kh1[d + 2], S3b, 0, 0, 0);
          S2a = __builtin_amdgcn_mfma_f32_16x16x32_f16(qfh[d], ke0[d], S2a, 0, 0, 0);
          S2b = __builtin_amdgcn_mfma_f32_16x16x32_f16(qfh[d + 2], ke0[d + 2], S2b, 0, 0, 0);
          S3a = __builtin_amdgcn_mfma_f32_16x16x32_f16(qfh[d], ke1[d], S3a, 0, 0, 0);
          S3b = __builtin_amdgcn_mfma_f32_16x16x32_f16(qfh[d + 2], ke1[d + 2], S3b, 0, 0, 0);
        }
        S2 = S2a + S2b;
        S3 = S3a + S3b;
      }

      // ---- scores for all 64 cols; ONE softmax epilogue for the pair ----
      float sc0[4], sc1[4], sc2[4], sc3[4];
      for (int r = 0; r < 4; ++r) {
        int i = i0 + quad * 4 + r;
        sc0[r] = (j0 + n <= i) ? (S0[r] * SCALE + biasA0[r]) : NEG9;
        sc1[r] = (j0 + 16 + n <= i) ? (S1[r] * SCALE + biasA1[r]) : NEG9;
        if (haveB) {
          sc2[r] = (j0 + 32 + n <= i) ? (S2[r] * SCALE + biasB0[r]) : NEG9;
          sc3[r] = (j0 + 48 + n <= i) ? (S3[r] * SCALE + biasB1[r]) : NEG9;
        }
      }
      float mx[4];
      for (int r = 0; r < 4; ++r) {
        mx[r] = fmaxf(sc0[r], sc1[r]);
        if (haveB) mx[r] = fmaxf(mx[r], fmaxf(sc2[r], sc3[r]));
      }
      for (int d = 1; d < 16; d <<= 1)
        for (int r = 0; r < 4; ++r) mx[r] = fmaxf(mx[r], __shfl_xor(mx[r], d, 64));
      float alpha[4];
      _Float16 phA0[4], phA1[4], phB0[4], phB1[4];
      for (int r = 0; r < 4; ++r) {
        float mnew = fmaxf(m_[r], mx[r]);
        alpha[r] = __expf(m_[r] - mnew);  // -inf -> 0
        phA0[r] = (_Float16)__expf(sc0[r] - mnew);
        phA1[r] = (_Float16)__expf(sc1[r] - mnew);
        if (haveB) {
          phB0[r] = (_Float16)__expf(sc2[r] - mnew);
          phB1[r] = (_Float16)__expf(sc3[r] - mnew);
        } else {
          phB0[r] = (_Float16)0.0f;
          phB1[r] = (_Float16)0.0f;
        }
        m_[r] = mnew;
      }

      // ---- P write EARLY (64-wide); LDS latency overlaps lsum tree ----
      for (int r = 0; r < 4; ++r) {
        PsW[(quad * 4 + r) * 64 + n] = phA0[r];
        PsW[(quad * 4 + r) * 64 + n + 16] = phA1[r];
        PsW[(quad * 4 + r) * 64 + n + 32] = phB0[r];
        PsW[(quad * 4 + r) * 64 + n + 48] = phB1[r];
      }

      float lsum[4];
      for (int r = 0; r < 4; ++r)
        lsum[r] = ((float)phA0[r] + (float)phA1[r]) +
                  ((float)phB0[r] + (float)phB1[r]);
      for (int d = 1; d < 16; d <<= 1)
        for (int r = 0; r < 4; ++r) lsum[r] += __shfl_xor(lsum[r], d, 64);
      for (int r = 0; r < 4; ++r) l_[r] = l_[r] * alpha[r] + lsum[r];
      for (int t = 0; t < 8; ++t)
        for (int r = 0; r < 4; ++r) acc[t][r] *= alpha[r];

      __builtin_amdgcn_sched_barrier(0);
      __builtin_amdgcn_s_waitcnt(0xC07F);  // lgkmcnt(0) only
      __builtin_amdgcn_sched_barrier(0);
      half8 pfA = *(half8*)&PsW[n * 64 + quad * 8];
      half8 pfB = *(half8*)&PsW[n * 64 + 32 + quad * 8];

      // ---- P @ V, chunk A then chunk B (V registers reused) ----
      {
        const _Float16* vbase = &Vt[(size_t)((h * HD) + n) * VT_STRIDE + j0 + quad * 8];
        half8 vf[8];
#pragma unroll
        for (int t = 0; t < 8; ++t)
          vf[t] = *(const half8*)&vbase[(size_t)t * 16 * VT_STRIDE];
#pragma unroll
        for (int t = 0; t < 8; ++t)
          acc[t] = __builtin_amdgcn_mfma_f32_16x16x32_f16(pfA, vf[t], acc[t], 0, 0, 0);
        if (haveB) {
#pragma unroll
          for (int t = 0; t < 8; ++t)
            vf[t] = *(const half8*)&vbase[32 + (size_t)t * 16 * VT_STRIDE];
#pragma unroll
          for (int t = 0; t < 8; ++t)
            acc[t] = __builtin_amdgcn_mfma_f32_16x16x32_f16(pfB, vf[t], acc[t], 0, 0, 0);
        }
      }
    }
  }

  // ---- block-level merge of 4 waves (Obuf overwrites each wave's own Ps) ----
  if (n == 0) {
    for (int r = 0; r < 4; ++r) {
      mW[w][quad * 4 + r] = m_[r];
      lW[w][quad * 4 + r] = l_[r];
    }
  }
  __syncthreads();  // all waves done with their Ps before Obuf phase reads begin
  for (int t = 0; t < 8; ++t)
    for (int r = 0; r < 4; ++r) Obuf[w][quad * 4 + r][t * 16 + n] = acc[t][r];
  __syncthreads();

  if (tid < 16) {
    int r = tid;
    float M = fmaxf(fmaxf(mW[0][r], mW[1][r]), fmaxf(mW[2][r], mW[3][r]));
    float L = 0.f;
    for (int s = 0; s < 4; ++s) {
      float es = (M == -INFINITY) ? 0.0f : expf(mW[s][r] - M);
      esW[s][r] = es;
      L += lW[s][r] * es;
    }
    Mrow[r] = M;
    Lrow[r] = L;
  }
  __syncthreads();

  if (ns == 1) {
    // whole tile in this block: finalize directly
    if (tid < 16) {
      int dead = (Mrow[tid] < ALIVE_MIN) ? 1 : 0;
      deadS[tid] = dead;
      LinvS[tid] = dead ? 0.0f : 1.0f / Lrow[tid];
    }
    if (tid >= 128 && tid < 256) {
      int d = tid - 128;
      VsS[d] = Vpart[(h * 4 + 0) * 128 + d] + Vpart[(h * 4 + 1) * 128 + d] +
               Vpart[(h * 4 + 2) * 128 + d] + Vpart[(h * 4 + 3) * 128 + d];
    }
    __syncthreads();
    for (int idx = tid; idx < 16 * 128; idx += 256) {
      int r = idx >> 7, d = idx & 127;
      float o;
      if (deadS[r]) {
        o = VsS[d] * 0.000244140625f;  // exact uniform softmax over 4096
      } else {
        o = (Obuf[0][r][d] * esW[0][r] + Obuf[1][r][d] * esW[1][r] +
             Obuf[2][r][d] * esW[2][r] + Obuf[3][r][d] * esW[3][r]) * LinvS[r];
      }
      out[(size_t)((h * T_SEQ) + i0 + r) * HD + d] = o;
    }
    return;
  }

  // ---- write partial (m, l fp32; O fp16); separate reduce kernel merges ----
  const size_t pbase = (size_t)(h * NPART_H + p);
  if (tid < 16) {
    Pm[pbase * 16 + tid] = Mrow[tid];
    Pl[pbase * 16 + tid] = Lrow[tid];
  }
  for (int idx = tid; idx < 16 * 128; idx += 256) {
    int r = idx >> 7, d = idx & 127;
    float o = Obuf[0][r][d] * esW[0][r] + Obuf[1][r][d] * esW[1][r] +
              Obuf[2][r][d] * esW[2][r] + Obuf[3][r][d] * esW[3][r];
    Po[pbase * 2048 + idx] = (_Float16)o;
  }
}

// ---------------- Reduce: merge ns partials per tile (rt >= 32 only) ----------------
__global__ __launch_bounds__(256) void reduce2_kernel(const float* __restrict__ Pm,
                                                      const float* __restrict__ Pl,
                                                      const _Float16* __restrict__ Po,
                                                      const float* __restrict__ Vpart,
                                                      float* __restrict__ out) {
  const int rt = 32 + (int)blockIdx.x, h = blockIdx.y;
  const int a = rt >> 5;
  const int ns = a + 1;
  const int base0 = 16 * a * (a + 1) + (rt & 31) * ns;
  const int tid = threadIdx.x;

  __shared__ float esP[8][16], LinvS[16], VsS[128];
  __shared__ int deadS[16];

  if (tid < 16) {
    int r = tid;
    float m[8], M = -INFINITY;
    for (int s = 0; s < ns; ++s) {
      m[s] = Pm[(size_t)(h * NPART_H + base0 + s) * 16 + r];
      M = fmaxf(M, m[s]);
    }
    int dead = (M < ALIVE_MIN) ? 1 : 0;
    deadS[r] = dead;
    float L = 0.f;
    for (int s = 0; s < ns; ++s) {
      float es = (dead || m[s] == -INFINITY) ? 0.0f : expf(m[s] - M);
      esP[s][r] = es;
      L += Pl[(size_t)(h * NPART_H + base0 + s) * 16 + r] * es;
    }
    LinvS[r] = dead ? 0.0f : 1.0f / L;
  }
  if (tid >= 128 && tid < 256) {
    int d = tid - 128;
    VsS[d] = Vpart[(h * 4 + 0) * 128 + d] + Vpart[(h * 4 + 1) * 128 + d] +
             Vpart[(h * 4 + 2) * 128 + d] + Vpart[(h * 4 + 3) * 128 + d];
  }
  __syncthreads();

  for (int idx = tid; idx < 16 * 128; idx += 256) {
    int r = idx >> 7, d = idx & 127;
    float o;
    if (deadS[r]) {
      o = VsS[d] * 0.000244140625f;
    } else {
      o = 0.f;
      for (int s = 0; s < ns; ++s)
        o += (float)Po[(size_t)(h * NPART_H + base0 + s) * 2048 + idx] * esP[s][r];
      o *= LinvS[r];
    }
    out[(size_t)((h * T_SEQ) + rt * 16 + r) * HD + d] = o;
  }
}

extern "C" void kernel_launch(void* const* d_in, const int* in_sizes, int n_in,
                              void* d_out, int out_size, void* d_ws, size_t ws_size,
                              hipStream_t stream) {
  const float* Q = (const float*)d_in[0];
  const float* K = (const float*)d_in[1];
  const float* V = (const float*)d_in[2];
  const float* U = (const float*)d_in[3];
  float* out = (float*)d_out;

  char* wsb = (char*)d_ws;
  float* sds = (float*)wsb;                        // 4 MB
  float* thrG = (float*)(wsb + 4194304);           // 8 KB
  float* bmax16 = (float*)(wsb + 4202496);         // 512 KB
  float* Vpart = (float*)(wsb + 4726784);          // 8 KB
  _Float16* Kh = (_Float16*)(wsb + 4734976);       // 4 MB
  _Float16* Ke = Kh + 2097152;                     // 4 MB
  _Float16* Vt = Ke + 2097152;                     // 4 MB
  float* Pm = (float*)(wsb + 17317888);            // 288 KB
  float* Pl = (float*)(wsb + 17612800);            // 288 KB
  _Float16* Po = (_Float16*)(wsb + 17907712);      // 18.9 MB -> total ~35.1 MB

  prep_kernel<<<3088, 256, 0, stream>>>(K, V, Kh, Ke, Vt, Vpart);
  sds_kernel<<<dim3(DS / 16, DS / 16, NH), dim3(16, 16), 0, stream>>>(Q, K, sds);
  bmaxthr_kernel<<<dim3(NRT, NH), 256, 0, stream>>>(sds, U, thrG, bmax16);
  attn14_kernel<<<dim3(NPART_H, NH), 256, 0, stream>>>(Q, Kh, Ke, Vt, U, sds, thrG,
                                                       bmax16, Pm, Pl, Po, Vpart, out);
  reduce2_kernel<<<dim3(NRT - 32, NH), 256, 0, stream>>>(Pm, Pl, Po, Vpart, out);
}

// Round 16
// 417.408 us; speedup vs baseline: 1.1080x; 1.1080x over previous
//
#include <hip/hip_runtime.h>
#include <math.h>

#define T_SEQ 4096
#define HD 128
#define NH 4
#define DS 512
#define SCALE 0.08838834764831845f
#define NEG9 (-1.0e9f)
#define BN 32
#define VT_STRIDE 4096
#define NCH 128        // T_SEQ / BN
#define NRT 256        // T_SEQ / 16
#define SEGC 16        // chunks per j-segment
#define NPART_H 1152   // sum over rt of ns(rt) = rt/32+1
#define ALIVE_MIN (-999999936.0f)  // smallest fp32 score an alive row can have

typedef __attribute__((ext_vector_type(8))) _Float16 half8;
typedef __attribute__((ext_vector_type(4))) float floatx4;

__device__ __forceinline__ float sigmoidf_(float x) {
  if (x >= 0.0f) return 1.0f / (1.0f + expf(-x));
  float e = expf(x);
  return e / (1.0f + e);
}

// ---------------- fused prep + sds: K h+e cvt, V transpose, V sums, ds scores ----------------
// bx < 1024: K split | < 3072: Vt | < 3088: vsum | >= 3088: sds (4096 blocks)
__global__ __launch_bounds__(256) void prepsds_kernel(
    const float* __restrict__ Q, const float* __restrict__ K, const float* __restrict__ V,
    _Float16* __restrict__ Kh, _Float16* __restrict__ Ke,
    _Float16* __restrict__ Vt, float* __restrict__ Vpart, float* __restrict__ sds) {
  const int bx = blockIdx.x, tid = threadIdx.x;
  __shared__ float tile[32][33];
  __shared__ float red[2][128];
  __shared__ float Qs[16][132];
  __shared__ float Ks[16][132];
  if (bx < 1024) {  // fp32 -> fp16 h+e split for K
    int idx = (bx * 256 + tid) * 8;
    float4 a = *(const float4*)&K[idx];
    float4 b = *(const float4*)&K[idx + 4];
    float v[8] = {a.x, a.y, a.z, a.w, b.x, b.y, b.z, b.w};
    half8 oh, oe;
#pragma unroll
    for (int t = 0; t < 8; ++t) {
      _Float16 hh = (_Float16)v[t];
      oh[t] = hh;
      oe[t] = (_Float16)(v[t] - (float)hh);
    }
    *(half8*)&Kh[idx] = oh;
    *(half8*)&Ke[idx] = oe;
  } else if (bx < 3072) {  // V transpose -> Vt fp16
    int b = bx - 1024;
    int jt = b & 127, dt = (b >> 7) & 3, h = b >> 9;
    int tx = tid & 31, ty = tid >> 5;
    for (int k = 0; k < 4; ++k) {
      int row = jt * 32 + ty + k * 8;
      tile[ty + k * 8][tx] = V[((h * T_SEQ) + row) * HD + dt * 32 + tx];
    }
    __syncthreads();
    for (int k = 0; k < 4; ++k) {
      int d = dt * 32 + ty + k * 8;
      int j = jt * 32 + tx;
      Vt[((size_t)(h * HD) + d) * VT_STRIDE + j] = (_Float16)tile[tx][ty + k * 8];
    }
  } else if (bx < 3088) {  // V column partial sums
    int b = bx - 3072;
    int h = b >> 2, part = b & 3;
    int d = tid & 127, hlf = tid >> 7;
    float s = 0.f;
    for (int j = part * 1024 + hlf; j < part * 1024 + 1024; j += 2)
      s += V[(size_t)((h * T_SEQ) + j) * HD + d];
    red[hlf][d] = s;
    __syncthreads();
    if (tid < 128)
      Vpart[(h * 4 + part) * 128 + tid] = red[0][tid] + red[1][tid];
  } else {  // downsampled scores (fp32, bit-identical to old sds_kernel)
    int b = bx - 3088;
    const int bxs = b & 31, bys = (b >> 5) & 31, h = b >> 10;
    for (int t = tid; t < 512; t += 256) {
      int r = t >> 5, f = (t & 31) * 4;
      *(float4*)&Qs[r][f] = *(const float4*)&Q[((h * T_SEQ) + (bys * 16 + r) * 8) * HD + f];
      *(float4*)&Ks[r][f] = *(const float4*)&K[((h * T_SEQ) + (bxs * 16 + r) * 8) * HD + f];
    }
    __syncthreads();
    const int ty = tid >> 4, tx = tid & 15;
    float acc = 0.0f;
    for (int k = 0; k < 32; ++k) {
      float4 a = *(float4*)&Qs[ty][k * 4];
      float4 bq = *(float4*)&Ks[tx][k * 4];
      acc += a.x * bq.x + a.y * bq.y + a.z * bq.z + a.w * bq.w;
    }
    sds[((h * DS) + bys * 16 + ty) * DS + bxs * 16 + tx] = acc * SCALE;
  }
}

// ---------------- Kernel B: fused exact 128th-largest (waves 0/1) + bias max ----------------
__global__ __launch_bounds__(256) void bmaxthr_kernel(const float* __restrict__ sds,
                                                      const float* __restrict__ U,
                                                      float* __restrict__ thrG,
                                                      float* __restrict__ bmax16) {
  const int h = blockIdx.y, rt = blockIdx.x;
  const int tid = threadIdx.x, ww = tid >> 6, lane = tid & 63;
  __shared__ float thrS[2];
  if (ww < 2) {  // radix select for ds-rows 2rt, 2rt+1 (bit-identical sequence)
    const int row = h * DS + rt * 2 + ww;
    unsigned v[8];
    for (int t = 0; t < 8; ++t) {
      float f = sds[(size_t)row * DS + t * 64 + lane];
      unsigned b = __float_as_uint(f);
      v[t] = (b & 0x80000000u) ? ~b : (b | 0x80000000u);
    }
    unsigned prefix = 0u;
    for (int bit = 31; bit >= 0; --bit) {
      unsigned cand = prefix | (1u << bit);
      int c = 0;
      for (int t = 0; t < 8; ++t) c += (v[t] >= cand) ? 1 : 0;
      for (int off = 32; off > 0; off >>= 1) c += __shfl_down(c, off, 64);
      c = __shfl(c, 0, 64);
      if (c >= 128) prefix = cand;
    }
    if (lane == 0) {
      unsigned b = (prefix & 0x80000000u) ? (prefix ^ 0x80000000u) : ~prefix;
      float t = __uint_as_float(b);
      thrS[ww] = t;
      thrG[row] = t;
    }
  }
  __syncthreads();
  // bias-max phase (bit-identical bias sequence)
  const int r = lane >> 2, q = lane & 3;
  const int i = rt * 16 + r;
  float u = U[i];
  u = fminf(fmaxf(u, 0.0f), 1.0f);
  const float us = 1.0f + u;
  const int idl = r >> 3;
  const float bb = us * thrS[idl];
  const float* srow = &sds[((h * DS) + rt * 2 + idl) * DS];
  for (int c = ww; c < NCH; c += 4) {
    float sval = srow[(c << 2) + q];
    float a = us * sval;
    float bias = (1.0f - sigmoidf_((a - bb) * 10.0f)) * NEG9;
    for (int off = 1; off < 64; off <<= 1)
      bias = fmaxf(bias, __shfl_xor(bias, off, 64));
    if (lane == 0) bmax16[((h * NRT) + rt) * NCH + c] = bias;
  }
}

// ---------------- Kernel C: split-j MFMA flash attention (R14 body + alpha-skip) ----------------
__global__ __launch_bounds__(256) void attn15_kernel(
    const float* __restrict__ Qf, const _Float16* __restrict__ Kh,
    const _Float16* __restrict__ Ke, const _Float16* __restrict__ Vt,
    const float* __restrict__ U, const float* __restrict__ sds,
    const float* __restrict__ thrG, const float* __restrict__ bmax16,
    float* __restrict__ Pm, float* __restrict__ Pl, _Float16* __restrict__ Po,
    const float* __restrict__ Vpart, float* __restrict__ out) {
  const int h = blockIdx.y;
  const int p = NPART_H - 1 - (int)blockIdx.x;  // heavy tiles (large rt) first
  int a = 0;
  while (a < 7 && p >= 16 * (a + 1) * (a + 2)) ++a;
  const int ns = a + 1;
  const int off = p - 16 * a * (a + 1);
  const int q_ = off / ns;
  const int rt = 32 * a + q_;
  const int seg = off - q_ * ns;
  const int i0 = rt * 16;
  const int nchunks = (rt >> 1) + 1;
  const int c0 = seg * SEGC;
  const int len = min(SEGC, nchunks - c0);  // >= 1

  const int tid = threadIdx.x;
  const int w = tid >> 6;
  const int lane = tid & 63;
  const int quad = lane >> 4;
  const int n = lane & 15;

  __shared__ float Obuf[4][16][128];
  __shared__ _Float16 Ps[4][16][32];
  __shared__ float mW[4][16], lW[4][16], esW[4][16];
  __shared__ float Mrow[16], Lrow[16], LinvS[16], VsS[128];
  __shared__ int deadS[16];

  // per-row constants (rows quad*4+r); 4 rows of a quad share one ds-row
  const int myid = (i0 >> 3) + (quad >> 1);
  float us[4], bb[4];
  for (int r = 0; r < 4; ++r) {
    int i = i0 + quad * 4 + r;
    float u = U[i];
    u = fminf(fmaxf(u, 0.0f), 1.0f);
    us[r] = 1.0f + u;
    bb[r] = us[r] * thrG[h * DS + myid];
  }

  // Q A-fragments: in-kernel h+e split (bit-identical; validated R9-R14)
  half8 qfh[4], qfe[4];
  {
    const float* qrow = &Qf[(size_t)((h * T_SEQ) + i0 + n) * HD + quad * 8];
#pragma unroll
    for (int d = 0; d < 4; ++d) {
      float4 x0 = *(const float4*)&qrow[d * 32];
      float4 x1 = *(const float4*)&qrow[d * 32 + 4];
      float v[8] = {x0.x, x0.y, x0.z, x0.w, x1.x, x1.y, x1.z, x1.w};
      half8 hh, ee;
#pragma unroll
      for (int t = 0; t < 8; ++t) {
        _Float16 hv = (_Float16)v[t];
        hh[t] = hv;
        ee[t] = (_Float16)(v[t] - (float)hv);
      }
      qfh[d] = hh;
      qfe[d] = ee;
    }
  }

  floatx4 acc[8];
  for (int t = 0; t < 8; ++t) acc[t] = (floatx4){0.f, 0.f, 0.f, 0.f};
  float m_[4], l_[4];
  for (int r = 0; r < 4; ++r) { m_[r] = -INFINITY; l_[r] = 0.0f; }

  // planning: wave w owns chunks c0 + w + 4k, k < nMine (<= 4)
  const int nMine = (len > w) ? ((len - w + 3) >> 2) : 0;
  float bval = -3.0e38f;
  if (lane < nMine)
    bval = bmax16[((h * NRT) + rt) * NCH + c0 + w + (lane << 2)];
  const unsigned bits = (nMine > 0) ? ((1u << nMine) - 1u) : 0u;
  const unsigned hotMask = (unsigned)__ballot(lane < nMine && bval > -124.0f) & bits;
  const unsigned nullMask = (unsigned)__ballot(lane < nMine && bval == NEG9) & bits;
  const unsigned coldMask = bits & ~hotMask & ~nullMask;
  // null chunks: every score exactly -1e9f; alive-row weight <= e^-64 (ref too);
  // fully-dead rows resolved exactly at merge via uniform-softmax closed form.

  for (int sweep = 0; sweep < 2; ++sweep) {
    unsigned mask = (sweep == 0) ? hotMask : coldMask;
    while (mask) {
      const int cc = __builtin_ctz(mask);
      mask &= mask - 1u;
      if (sweep == 1) {
        float bm16 = __shfl(bval, cc, 64);
        float mm = fminf(fminf(m_[0], m_[1]), fminf(m_[2], m_[3]));
        mm = fminf(mm, __shfl_xor(mm, 16, 64));
        mm = fminf(mm, __shfl_xor(mm, 32, 64));
        if (bm16 + 12.0f < mm - 40.0f) continue;  // contribution < e^-40 relative
      }
      const int c = c0 + w + (cc << 2);
      const int j0 = c * BN;

      // ---- issue ALL loads up front: sds -> Kh -> Ke -> V ----
      const int br = n & 3;
      const int bjd = n >> 2;
      const float sval = sds[((h * DS) + myid) * DS + (c << 2) + bjd];

      const size_t kbase = (size_t)((h * T_SEQ) + j0 + n) * HD + quad * 8;
      half8 kh0[4], kh1[4];
#pragma unroll
      for (int d = 0; d < 4; ++d) {
        kh0[d] = *(const half8*)&Kh[kbase + d * 32];
        kh1[d] = *(const half8*)&Kh[kbase + 16 * HD + d * 32];
      }
      half8 ke0[4], ke1[4];
#pragma unroll
      for (int d = 0; d < 4; ++d) {
        ke0[d] = *(const half8*)&Ke[kbase + d * 32];
        ke1[d] = *(const half8*)&Ke[kbase + 16 * HD + d * 32];
      }
      const _Float16* vbase = &Vt[(size_t)((h * HD) + n) * VT_STRIDE + j0 + quad * 8];
      half8 vf[8];
#pragma unroll
      for (int t = 0; t < 8; ++t)
        vf[t] = *(const half8*)&vbase[(size_t)t * 16 * VT_STRIDE];

      // ---- bias: one sigmoid/lane, bit-identical values (R13), gathered by shuffle ----
      const float aa = us[br] * sval;
      const float myBias = (1.0f - sigmoidf_((aa - bb[br]) * 10.0f)) * NEG9;
      float biasA[4], biasB[4];
      {
        const int baseLane = (quad << 4) + ((n >> 3) << 2);
#pragma unroll
        for (int r = 0; r < 4; ++r) {
          biasA[r] = __shfl(myBias, baseLane + r, 64);
          biasB[r] = __shfl(myBias, baseLane + 8 + r, 64);
        }
      }

      // ---- QK^T: 3-term fp16 split, 24 mfma, SPLIT accumulators (2x 6-deep chains) ----
      floatx4 S0a = (floatx4){0.f, 0.f, 0.f, 0.f};
      floatx4 S0b = (floatx4){0.f, 0.f, 0.f, 0.f};
      floatx4 S1a = (floatx4){0.f, 0.f, 0.f, 0.f};
      floatx4 S1b = (floatx4){0.f, 0.f, 0.f, 0.f};
      S0a = __builtin_amdgcn_mfma_f32_16x16x32_f16(qfh[0], kh0[0], S0a, 0, 0, 0);
      S0b = __builtin_amdgcn_mfma_f32_16x16x32_f16(qfh[2], kh0[2], S0b, 0, 0, 0);
      S1a = __builtin_amdgcn_mfma_f32_16x16x32_f16(qfh[0], kh1[0], S1a, 0, 0, 0);
      S1b = __builtin_amdgcn_mfma_f32_16x16x32_f16(qfh[2], kh1[2], S1b, 0, 0, 0);
      S0a = __builtin_amdgcn_mfma_f32_16x16x32_f16(qfh[1], kh0[1], S0a, 0, 0, 0);
      S0b = __builtin_amdgcn_mfma_f32_16x16x32_f16(qfh[3], kh0[3], S0b, 0, 0, 0);
      S1a = __builtin_amdgcn_mfma_f32_16x16x32_f16(qfh[1], kh1[1], S1a, 0, 0, 0);
      S1b = __builtin_amdgcn_mfma_f32_16x16x32_f16(qfh[3], kh1[3], S1b, 0, 0, 0);

      S0a = __builtin_amdgcn_mfma_f32_16x16x32_f16(qfe[0], kh0[0], S0a, 0, 0, 0);
      S0b = __builtin_amdgcn_mfma_f32_16x16x32_f16(qfe[2], kh0[2], S0b, 0, 0, 0);
      S1a = __builtin_amdgcn_mfma_f32_16x16x32_f16(qfe[0], kh1[0], S1a, 0, 0, 0);
      S1b = __builtin_amdgcn_mfma_f32_16x16x32_f16(qfe[2], kh1[2], S1b, 0, 0, 0);
      S0a = __builtin_amdgcn_mfma_f32_16x16x32_f16(qfe[1], kh0[1], S0a, 0, 0, 0);
      S0b = __builtin_amdgcn_mfma_f32_16x16x32_f16(qfe[3], kh0[3], S0b, 0, 0, 0);
      S1a = __builtin_amdgcn_mfma_f32_16x16x32_f16(qfe[1], kh1[1], S1a, 0, 0, 0);
      S1b = __builtin_amdgcn_mfma_f32_16x16x32_f16(qfe[3], kh1[3], S1b, 0, 0, 0);

      S0a = __builtin_amdgcn_mfma_f32_16x16x32_f16(qfh[0], ke0[0], S0a, 0, 0, 0);
      S0b = __builtin_amdgcn_mfma_f32_16x16x32_f16(qfh[2], ke0[2], S0b, 0, 0, 0);
      S1a = __builtin_amdgcn_mfma_f32_16x16x32_f16(qfh[0], ke1[0], S1a, 0, 0, 0);
      S1b = __builtin_amdgcn_mfma_f32_16x16x32_f16(qfh[2], ke1[2], S1b, 0, 0, 0);
      S0a = __builtin_amdgcn_mfma_f32_16x16x32_f16(qfh[1], ke0[1], S0a, 0, 0, 0);
      S0b = __builtin_amdgcn_mfma_f32_16x16x32_f16(qfh[3], ke0[3], S0b, 0, 0, 0);
      S1a = __builtin_amdgcn_mfma_f32_16x16x32_f16(qfh[1], ke1[1], S1a, 0, 0, 0);
      S1b = __builtin_amdgcn_mfma_f32_16x16x32_f16(qfh[3], ke1[3], S1b, 0, 0, 0);

      const floatx4 S0 = S0a + S0b;  // ~1-ulp score reorder; smooth softmax path only
      const floatx4 S1 = S1a + S1b;

      // ---- scores & online softmax ----
      const int jA = j0 + n, jB = j0 + 16 + n;
      float sc0[4], sc1[4];
      for (int r = 0; r < 4; ++r) {
        int i = i0 + quad * 4 + r;
        sc0[r] = (jA <= i) ? (S0[r] * SCALE + biasA[r]) : NEG9;
        sc1[r] = (jB <= i) ? (S1[r] * SCALE + biasB[r]) : NEG9;
      }
      float mx[4];
      for (int r = 0; r < 4; ++r) mx[r] = fmaxf(sc0[r], sc1[r]);
      for (int d = 1; d < 16; d <<= 1)
        for (int r = 0; r < 4; ++r) mx[r] = fmaxf(mx[r], __shfl_xor(mx[r], d, 64));
      float alpha[4];
      _Float16 ph0[4], ph1[4];
      for (int r = 0; r < 4; ++r) {
        float mnew = fmaxf(m_[r], mx[r]);
        alpha[r] = __expf(m_[r] - mnew);  // -inf -> 0
        ph0[r] = (_Float16)__expf(sc0[r] - mnew);
        ph1[r] = (_Float16)__expf(sc1[r] - mnew);
        m_[r] = mnew;
      }

      // ---- P write EARLY: LDS latency overlaps the lsum tree below ----
      for (int r = 0; r < 4; ++r) {
        Ps[w][quad * 4 + r][n] = ph0[r];
        Ps[w][quad * 4 + r][n + 16] = ph1[r];
      }

      float lsum[4];
      for (int r = 0; r < 4; ++r) lsum[r] = (float)ph0[r] + (float)ph1[r];
      for (int d = 1; d < 16; d <<= 1)
        for (int r = 0; r < 4; ++r) lsum[r] += __shfl_xor(lsum[r], d, 64);
      for (int r = 0; r < 4; ++r) l_[r] = l_[r] * alpha[r] + lsum[r];
      // alpha-skip: when alpha==1 wave-wide, the rescale is an fp32 identity — skip it
      bool needResc = false;
      for (int r = 0; r < 4; ++r) needResc |= (alpha[r] != 1.0f);
      if (__any(needResc)) {
        for (int t = 0; t < 8; ++t)
          for (int r = 0; r < 4; ++r) acc[t][r] *= alpha[r];
      }

      __builtin_amdgcn_sched_barrier(0);
      __builtin_amdgcn_s_waitcnt(0xC07F);  // lgkmcnt(0) only
      __builtin_amdgcn_sched_barrier(0);
      half8 pf = *(half8*)&Ps[w][n][quad * 8];

      // ---- P @ V (V already in registers) ----
#pragma unroll
      for (int t = 0; t < 8; ++t)
        acc[t] = __builtin_amdgcn_mfma_f32_16x16x32_f16(pf, vf[t], acc[t], 0, 0, 0);
    }
  }

  // ---- block-level merge of 4 waves ----
  if (n == 0) {
    for (int r = 0; r < 4; ++r) {
      mW[w][quad * 4 + r] = m_[r];
      lW[w][quad * 4 + r] = l_[r];
    }
  }
  for (int t = 0; t < 8; ++t)
    for (int r = 0; r < 4; ++r) Obuf[w][quad * 4 + r][t * 16 + n] = acc[t][r];
  __syncthreads();

  if (tid < 16) {
    int r = tid;
    float M = fmaxf(fmaxf(mW[0][r], mW[1][r]), fmaxf(mW[2][r], mW[3][r]));
    float L = 0.f;
    for (int s = 0; s < 4; ++s) {
      float es = (M == -INFINITY) ? 0.0f : expf(mW[s][r] - M);
      esW[s][r] = es;
      L += lW[s][r] * es;
    }
    Mrow[r] = M;
    Lrow[r] = L;
  }
  __syncthreads();

  if (ns == 1) {
    // whole tile in this block: finalize directly
    if (tid < 16) {
      int dead = (Mrow[tid] < ALIVE_MIN) ? 1 : 0;
      deadS[tid] = dead;
      LinvS[tid] = dead ? 0.0f : 1.0f / Lrow[tid];
    }
    if (tid >= 128 && tid < 256) {
      int d = tid - 128;
      VsS[d] = Vpart[(h * 4 + 0) * 128 + d] + Vpart[(h * 4 + 1) * 128 + d] +
               Vpart[(h * 4 + 2) * 128 + d] + Vpart[(h * 4 + 3) * 128 + d];
    }
    __syncthreads();
    for (int idx = tid; idx < 16 * 128; idx += 256) {
      int r = idx >> 7, d = idx & 127;
      float o;
      if (deadS[r]) {
        o = VsS[d] * 0.000244140625f;  // exact uniform softmax over 4096
      } else {
        o = (Obuf[0][r][d] * esW[0][r] + Obuf[1][r][d] * esW[1][r] +
             Obuf[2][r][d] * esW[2][r] + Obuf[3][r][d] * esW[3][r]) * LinvS[r];
      }
      out[(size_t)((h * T_SEQ) + i0 + r) * HD + d] = o;
    }
    return;
  }

  // ---- write partial (m, l fp32; O fp16); separate reduce kernel merges ----
  const size_t pbase = (size_t)(h * NPART_H + p);
  if (tid < 16) {
    Pm[pbase * 16 + tid] = Mrow[tid];
    Pl[pbase * 16 + tid] = Lrow[tid];
  }
  for (int idx = tid; idx < 16 * 128; idx += 256) {
    int r = idx >> 7, d = idx & 127;
    float o = Obuf[0][r][d] * esW[0][r] + Obuf[1][r][d] * esW[1][r] +
              Obuf[2][r][d] * esW[2][r] + Obuf[3][r][d] * esW[3][r];
    Po[pbase * 2048 + idx] = (_Float16)o;
  }
}

// ---------------- Reduce: merge ns partials per tile (rt >= 32 only) ----------------
__global__ __launch_bounds__(256) void reduce2_kernel(const float* __restrict__ Pm,
                                                      const float* __restrict__ Pl,
                                                      const _Float16* __restrict__ Po,
                                                      const float* __restrict__ Vpart,
                                                      float* __restrict__ out) {
  const int rt = 32 + (int)blockIdx.x, h = blockIdx.y;
  const int a = rt >> 5;
  const int ns = a + 1;
  const int base0 = 16 * a * (a + 1) + (rt & 31) * ns;
  const int tid = threadIdx.x;

  __shared__ float esP[8][16], LinvS[16], VsS[128];
  __shared__ int deadS[16];

  if (tid < 16) {
    int r = tid;
    float m[8], M = -INFINITY;
    for (int s = 0; s < ns; ++s) {
      m[s] = Pm[(size_t)(h * NPART_H + base0 + s) * 16 + r];
      M = fmaxf(M, m[s]);
    }
    int dead = (M < ALIVE_MIN) ? 1 : 0;
    deadS[r] = dead;
    float L = 0.f;
    for (int s = 0; s < ns; ++s) {
      float es = (dead || m[s] == -INFINITY) ? 0.0f : expf(m[s] - M);
      esP[s][r] = es;
      L += Pl[(size_t)(h * NPART_H + base0 + s) * 16 + r] * es;
    }
    LinvS[r] = dead ? 0.0f : 1.0f / L;
  }
  if (tid >= 128 && tid < 256) {
    int d = tid - 128;
    VsS[d] = Vpart[(h * 4 + 0) * 128 + d] + Vpart[(h * 4 + 1) * 128 + d] +
             Vpart[(h * 4 + 2) * 128 + d] + Vpart[(h * 4 + 3) * 128 + d];
  }
  __syncthreads();

  for (int idx = tid; idx < 16 * 128; idx += 256) {
    int r = idx >> 7, d = idx & 127;
    float o;
    if (deadS[r]) {
      o = VsS[d] * 0.000244140625f;
    } else {
      o = 0.f;
      for (int s = 0; s < ns; ++s)
        o += (float)Po[(size_t)(h * NPART_H + base0 + s) * 2048 + idx] * esP[s][r];
      o *= LinvS[r];
    }
    out[(size_t)((h * T_SEQ) + rt * 16 + r) * HD + d] = o;
  }
}

extern "C" void kernel_launch(void* const* d_in, const int* in_sizes, int n_in,
                              void* d_out, int out_size, void* d_ws, size_t ws_size,
                              hipStream_t stream) {
  const float* Q = (const float*)d_in[0];
  const float* K = (const float*)d_in[1];
  const float* V = (const float*)d_in[2];
  const float* U = (const float*)d_in[3];
  float* out = (float*)d_out;

  char* wsb = (char*)d_ws;
  float* sds = (float*)wsb;                        // 4 MB
  float* thrG = (float*)(wsb + 4194304);           // 8 KB
  float* bmax16 = (float*)(wsb + 4202496);         // 512 KB
  float* Vpart = (float*)(wsb + 4726784);          // 8 KB
  _Float16* Kh = (_Float16*)(wsb + 4734976);       // 4 MB
  _Float16* Ke = Kh + 2097152;                     // 4 MB
  _Float16* Vt = Ke + 2097152;                     // 4 MB
  float* Pm = (float*)(wsb + 17317888);            // 288 KB
  float* Pl = (float*)(wsb + 17612800);            // 288 KB
  _Float16* Po = (_Float16*)(wsb + 17907712);      // 18.9 MB -> total ~35.1 MB

  prepsds_kernel<<<7184, 256, 0, stream>>>(Q, K, V, Kh, Ke, Vt, Vpart, sds);
  bmaxthr_kernel<<<dim3(NRT, NH), 256, 0, stream>>>(sds, U, thrG, bmax16);
  attn15_kernel<<<dim3(NPART_H, NH), 256, 0, stream>>>(Q, Kh, Ke, Vt, U, sds, thrG,
                                                       bmax16, Pm, Pl, Po, Vpart, out);
  reduce2_kernel<<<dim3(NRT - 32, NH), 256, 0, stream>>>(Pm, Pl, Po, Vpart, out);
}

// Round 17
// 308.089 us; speedup vs baseline: 1.5012x; 1.3548x over previous
//
#include <hip/hip_runtime.h>
#include <math.h>

#define T_SEQ 4096
#define HD 128
#define NH 4
#define DS 512
#define SCALE 0.08838834764831845f
#define NEG9 (-1.0e9f)
#define BN 32
#define VT_STRIDE 4096
#define NCH 128        // T_SEQ / BN
#define NRT 256        // T_SEQ / 16
#define SEGC 16        // chunks per j-segment
#define NPART_H 1152   // sum over rt of ns(rt) = rt/32+1
#define NVP 32         // V-sum parts per head (128 rows each)
#define ALIVE_MIN (-999999936.0f)  // smallest fp32 score an alive row can have

typedef __attribute__((ext_vector_type(8))) _Float16 half8;
typedef __attribute__((ext_vector_type(4))) float floatx4;

__device__ __forceinline__ float sigmoidf_(float x) {
  if (x >= 0.0f) return 1.0f / (1.0f + expf(-x));
  float e = expf(x);
  return e / (1.0f + e);
}

// ---------------- fused prep + sds: K h+e cvt, V transpose, V sums, ds scores ----------------
// bx < 1024: K split | < 3072: Vt | < 3200: vsum (128 blocks) | >= 3200: sds (4096 blocks)
__global__ __launch_bounds__(256) void prepsds_kernel(
    const float* __restrict__ Q, const float* __restrict__ K, const float* __restrict__ V,
    _Float16* __restrict__ Kh, _Float16* __restrict__ Ke,
    _Float16* __restrict__ Vt, float* __restrict__ Vpart, float* __restrict__ sds) {
  const int bx = blockIdx.x, tid = threadIdx.x;
  __shared__ float tile[32][33];
  __shared__ float red[2][128];
  __shared__ float Qs[16][132];
  __shared__ float Ks[16][132];
  if (bx < 1024) {  // fp32 -> fp16 h+e split for K
    int idx = (bx * 256 + tid) * 8;
    float4 a = *(const float4*)&K[idx];
    float4 b = *(const float4*)&K[idx + 4];
    float v[8] = {a.x, a.y, a.z, a.w, b.x, b.y, b.z, b.w};
    half8 oh, oe;
#pragma unroll
    for (int t = 0; t < 8; ++t) {
      _Float16 hh = (_Float16)v[t];
      oh[t] = hh;
      oe[t] = (_Float16)(v[t] - (float)hh);
    }
    *(half8*)&Kh[idx] = oh;
    *(half8*)&Ke[idx] = oe;
  } else if (bx < 3072) {  // V transpose -> Vt fp16
    int b = bx - 1024;
    int jt = b & 127, dt = (b >> 7) & 3, h = b >> 9;
    int tx = tid & 31, ty = tid >> 5;
    for (int k = 0; k < 4; ++k) {
      int row = jt * 32 + ty + k * 8;
      tile[ty + k * 8][tx] = V[((h * T_SEQ) + row) * HD + dt * 32 + tx];
    }
    __syncthreads();
    for (int k = 0; k < 4; ++k) {
      int d = dt * 32 + ty + k * 8;
      int j = jt * 32 + tx;
      Vt[((size_t)(h * HD) + d) * VT_STRIDE + j] = (_Float16)tile[tx][ty + k * 8];
    }
  } else if (bx < 3200) {  // V column partial sums: 128 blocks, 128 rows each
    int b = bx - 3072;
    int h = b >> 5, part = b & 31;
    int d = tid & 127, hlf = tid >> 7;
    const int j0 = part * 128 + hlf;
    // two interleaved accumulators break the dependent-add chain
    float s0 = 0.f, s1 = 0.f;
    for (int j = j0; j < part * 128 + 128; j += 4) {
      s0 += V[(size_t)((h * T_SEQ) + j) * HD + d];
      s1 += V[(size_t)((h * T_SEQ) + j + 2) * HD + d];
    }
    red[hlf][d] = s0 + s1;
    __syncthreads();
    if (tid < 128)
      Vpart[(h * NVP + part) * 128 + tid] = red[0][tid] + red[1][tid];
  } else {  // downsampled scores (fp32, bit-identical to old sds_kernel)
    int b = bx - 3200;
    const int bxs = b & 31, bys = (b >> 5) & 31, h = b >> 10;
    for (int t = tid; t < 512; t += 256) {
      int r = t >> 5, f = (t & 31) * 4;
      *(float4*)&Qs[r][f] = *(const float4*)&Q[((h * T_SEQ) + (bys * 16 + r) * 8) * HD + f];
      *(float4*)&Ks[r][f] = *(const float4*)&K[((h * T_SEQ) + (bxs * 16 + r) * 8) * HD + f];
    }
    __syncthreads();
    const int ty = tid >> 4, tx = tid & 15;
    float acc = 0.0f;
    for (int k = 0; k < 32; ++k) {
      float4 a = *(float4*)&Qs[ty][k * 4];
      float4 bq = *(float4*)&Ks[tx][k * 4];
      acc += a.x * bq.x + a.y * bq.y + a.z * bq.z + a.w * bq.w;
    }
    sds[((h * DS) + bys * 16 + ty) * DS + bxs * 16 + tx] = acc * SCALE;
  }
}

// ---------------- Kernel B: fused exact 128th-largest (waves 0/1) + bias max ----------------
__global__ __launch_bounds__(256) void bmaxthr_kernel(const float* __restrict__ sds,
                                                      const float* __restrict__ U,
                                                      float* __restrict__ thrG,
                                                      float* __restrict__ bmax16) {
  const int h = blockIdx.y, rt = blockIdx.x;
  const int tid = threadIdx.x, ww = tid >> 6, lane = tid & 63;
  __shared__ float thrS[2];
  if (ww < 2) {  // radix select for ds-rows 2rt, 2rt+1 (bit-identical sequence)
    const int row = h * DS + rt * 2 + ww;
    unsigned v[8];
    for (int t = 0; t < 8; ++t) {
      float f = sds[(size_t)row * DS + t * 64 + lane];
      unsigned b = __float_as_uint(f);
      v[t] = (b & 0x80000000u) ? ~b : (b | 0x80000000u);
    }
    unsigned prefix = 0u;
    for (int bit = 31; bit >= 0; --bit) {
      unsigned cand = prefix | (1u << bit);
      int c = 0;
      for (int t = 0; t < 8; ++t) c += (v[t] >= cand) ? 1 : 0;
      for (int off = 32; off > 0; off >>= 1) c += __shfl_down(c, off, 64);
      c = __shfl(c, 0, 64);
      if (c >= 128) prefix = cand;
    }
    if (lane == 0) {
      unsigned b = (prefix & 0x80000000u) ? (prefix ^ 0x80000000u) : ~prefix;
      float t = __uint_as_float(b);
      thrS[ww] = t;
      thrG[row] = t;
    }
  }
  __syncthreads();
  // bias-max phase (bit-identical bias sequence)
  const int r = lane >> 2, q = lane & 3;
  const int i = rt * 16 + r;
  float u = U[i];
  u = fminf(fmaxf(u, 0.0f), 1.0f);
  const float us = 1.0f + u;
  const int idl = r >> 3;
  const float bb = us * thrS[idl];
  const float* srow = &sds[((h * DS) + rt * 2 + idl) * DS];
  for (int c = ww; c < NCH; c += 4) {
    float sval = srow[(c << 2) + q];
    float a = us * sval;
    float bias = (1.0f - sigmoidf_((a - bb) * 10.0f)) * NEG9;
    for (int off = 1; off < 64; off <<= 1)
      bias = fmaxf(bias, __shfl_xor(bias, off, 64));
    if (lane == 0) bmax16[((h * NRT) + rt) * NCH + c] = bias;
  }
}

// ---------------- Kernel C: split-j MFMA flash attention (R16 body) ----------------
__global__ __launch_bounds__(256) void attn16_kernel(
    const float* __restrict__ Qf, const _Float16* __restrict__ Kh,
    const _Float16* __restrict__ Ke, const _Float16* __restrict__ Vt,
    const float* __restrict__ U, const float* __restrict__ sds,
    const float* __restrict__ thrG, const float* __restrict__ bmax16,
    float* __restrict__ Pm, float* __restrict__ Pl, _Float16* __restrict__ Po,
    const float* __restrict__ Vpart, float* __restrict__ out) {
  const int h = blockIdx.y;
  const int p = NPART_H - 1 - (int)blockIdx.x;  // heavy tiles (large rt) first
  int a = 0;
  while (a < 7 && p >= 16 * (a + 1) * (a + 2)) ++a;
  const int ns = a + 1;
  const int off = p - 16 * a * (a + 1);
  const int q_ = off / ns;
  const int rt = 32 * a + q_;
  const int seg = off - q_ * ns;
  const int i0 = rt * 16;
  const int nchunks = (rt >> 1) + 1;
  const int c0 = seg * SEGC;
  const int len = min(SEGC, nchunks - c0);  // >= 1

  const int tid = threadIdx.x;
  const int w = tid >> 6;
  const int lane = tid & 63;
  const int quad = lane >> 4;
  const int n = lane & 15;

  __shared__ float Obuf[4][16][128];
  __shared__ _Float16 Ps[4][16][32];
  __shared__ float mW[4][16], lW[4][16], esW[4][16];
  __shared__ float Mrow[16], Lrow[16], LinvS[16], VsS[128];
  __shared__ int deadS[16];

  // per-row constants (rows quad*4+r); 4 rows of a quad share one ds-row
  const int myid = (i0 >> 3) + (quad >> 1);
  float us[4], bb[4];
  for (int r = 0; r < 4; ++r) {
    int i = i0 + quad * 4 + r;
    float u = U[i];
    u = fminf(fmaxf(u, 0.0f), 1.0f);
    us[r] = 1.0f + u;
    bb[r] = us[r] * thrG[h * DS + myid];
  }

  // Q A-fragments: in-kernel h+e split (bit-identical; validated R9-R16)
  half8 qfh[4], qfe[4];
  {
    const float* qrow = &Qf[(size_t)((h * T_SEQ) + i0 + n) * HD + quad * 8];
#pragma unroll
    for (int d = 0; d < 4; ++d) {
      float4 x0 = *(const float4*)&qrow[d * 32];
      float4 x1 = *(const float4*)&qrow[d * 32 + 4];
      float v[8] = {x0.x, x0.y, x0.z, x0.w, x1.x, x1.y, x1.z, x1.w};
      half8 hh, ee;
#pragma unroll
      for (int t = 0; t < 8; ++t) {
        _Float16 hv = (_Float16)v[t];
        hh[t] = hv;
        ee[t] = (_Float16)(v[t] - (float)hv);
      }
      qfh[d] = hh;
      qfe[d] = ee;
    }
  }

  floatx4 acc[8];
  for (int t = 0; t < 8; ++t) acc[t] = (floatx4){0.f, 0.f, 0.f, 0.f};
  float m_[4], l_[4];
  for (int r = 0; r < 4; ++r) { m_[r] = -INFINITY; l_[r] = 0.0f; }

  // planning: wave w owns chunks c0 + w + 4k, k < nMine (<= 4)
  const int nMine = (len > w) ? ((len - w + 3) >> 2) : 0;
  float bval = -3.0e38f;
  if (lane < nMine)
    bval = bmax16[((h * NRT) + rt) * NCH + c0 + w + (lane << 2)];
  const unsigned bits = (nMine > 0) ? ((1u << nMine) - 1u) : 0u;
  const unsigned hotMask = (unsigned)__ballot(lane < nMine && bval > -124.0f) & bits;
  const unsigned nullMask = (unsigned)__ballot(lane < nMine && bval == NEG9) & bits;
  const unsigned coldMask = bits & ~hotMask & ~nullMask;
  // null chunks: every score exactly -1e9f; alive-row weight <= e^-64 (ref too);
  // fully-dead rows resolved exactly at merge via uniform-softmax closed form.

  for (int sweep = 0; sweep < 2; ++sweep) {
    unsigned mask = (sweep == 0) ? hotMask : coldMask;
    while (mask) {
      const int cc = __builtin_ctz(mask);
      mask &= mask - 1u;
      if (sweep == 1) {
        float bm16 = __shfl(bval, cc, 64);
        float mm = fminf(fminf(m_[0], m_[1]), fminf(m_[2], m_[3]));
        mm = fminf(mm, __shfl_xor(mm, 16, 64));
        mm = fminf(mm, __shfl_xor(mm, 32, 64));
        if (bm16 + 12.0f < mm - 40.0f) continue;  // contribution < e^-40 relative
      }
      const int c = c0 + w + (cc << 2);
      const int j0 = c * BN;

      // ---- issue ALL loads up front: sds -> Kh -> Ke -> V ----
      const int br = n & 3;
      const int bjd = n >> 2;
      const float sval = sds[((h * DS) + myid) * DS + (c << 2) + bjd];

      const size_t kbase = (size_t)((h * T_SEQ) + j0 + n) * HD + quad * 8;
      half8 kh0[4], kh1[4];
#pragma unroll
      for (int d = 0; d < 4; ++d) {
        kh0[d] = *(const half8*)&Kh[kbase + d * 32];
        kh1[d] = *(const half8*)&Kh[kbase + 16 * HD + d * 32];
      }
      half8 ke0[4], ke1[4];
#pragma unroll
      for (int d = 0; d < 4; ++d) {
        ke0[d] = *(const half8*)&Ke[kbase + d * 32];
        ke1[d] = *(const half8*)&Ke[kbase + 16 * HD + d * 32];
      }
      const _Float16* vbase = &Vt[(size_t)((h * HD) + n) * VT_STRIDE + j0 + quad * 8];
      half8 vf[8];
#pragma unroll
      for (int t = 0; t < 8; ++t)
        vf[t] = *(const half8*)&vbase[(size_t)t * 16 * VT_STRIDE];

      // ---- bias: one sigmoid/lane, bit-identical values, gathered by shuffle ----
      const float aa = us[br] * sval;
      const float myBias = (1.0f - sigmoidf_((aa - bb[br]) * 10.0f)) * NEG9;
      float biasA[4], biasB[4];
      {
        const int baseLane = (quad << 4) + ((n >> 3) << 2);
#pragma unroll
        for (int r = 0; r < 4; ++r) {
          biasA[r] = __shfl(myBias, baseLane + r, 64);
          biasB[r] = __shfl(myBias, baseLane + 8 + r, 64);
        }
      }

      // ---- QK^T: 3-term fp16 split, 24 mfma, SPLIT accumulators (2x 6-deep chains) ----
      floatx4 S0a = (floatx4){0.f, 0.f, 0.f, 0.f};
      floatx4 S0b = (floatx4){0.f, 0.f, 0.f, 0.f};
      floatx4 S1a = (floatx4){0.f, 0.f, 0.f, 0.f};
      floatx4 S1b = (floatx4){0.f, 0.f, 0.f, 0.f};
      S0a = __builtin_amdgcn_mfma_f32_16x16x32_f16(qfh[0], kh0[0], S0a, 0, 0, 0);
      S0b = __builtin_amdgcn_mfma_f32_16x16x32_f16(qfh[2], kh0[2], S0b, 0, 0, 0);
      S1a = __builtin_amdgcn_mfma_f32_16x16x32_f16(qfh[0], kh1[0], S1a, 0, 0, 0);
      S1b = __builtin_amdgcn_mfma_f32_16x16x32_f16(qfh[2], kh1[2], S1b, 0, 0, 0);
      S0a = __builtin_amdgcn_mfma_f32_16x16x32_f16(qfh[1], kh0[1], S0a, 0, 0, 0);
      S0b = __builtin_amdgcn_mfma_f32_16x16x32_f16(qfh[3], kh0[3], S0b, 0, 0, 0);
      S1a = __builtin_amdgcn_mfma_f32_16x16x32_f16(qfh[1], kh1[1], S1a, 0, 0, 0);
      S1b = __builtin_amdgcn_mfma_f32_16x16x32_f16(qfh[3], kh1[3], S1b, 0, 0, 0);

      S0a = __builtin_amdgcn_mfma_f32_16x16x32_f16(qfe[0], kh0[0], S0a, 0, 0, 0);
      S0b = __builtin_amdgcn_mfma_f32_16x16x32_f16(qfe[2], kh0[2], S0b, 0, 0, 0);
      S1a = __builtin_amdgcn_mfma_f32_16x16x32_f16(qfe[0], kh1[0], S1a, 0, 0, 0);
      S1b = __builtin_amdgcn_mfma_f32_16x16x32_f16(qfe[2], kh1[2], S1b, 0, 0, 0);
      S0a = __builtin_amdgcn_mfma_f32_16x16x32_f16(qfe[1], kh0[1], S0a, 0, 0, 0);
      S0b = __builtin_amdgcn_mfma_f32_16x16x32_f16(qfe[3], kh0[3], S0b, 0, 0, 0);
      S1a = __builtin_amdgcn_mfma_f32_16x16x32_f16(qfe[1], kh1[1], S1a, 0, 0, 0);
      S1b = __builtin_amdgcn_mfma_f32_16x16x32_f16(qfe[3], kh1[3], S1b, 0, 0, 0);

      S0a = __builtin_amdgcn_mfma_f32_16x16x32_f16(qfh[0], ke0[0], S0a, 0, 0, 0);
      S0b = __builtin_amdgcn_mfma_f32_16x16x32_f16(qfh[2], ke0[2], S0b, 0, 0, 0);
      S1a = __builtin_amdgcn_mfma_f32_16x16x32_f16(qfh[0], ke1[0], S1a, 0, 0, 0);
      S1b = __builtin_amdgcn_mfma_f32_16x16x32_f16(qfh[2], ke1[2], S1b, 0, 0, 0);
      S0a = __builtin_amdgcn_mfma_f32_16x16x32_f16(qfh[1], ke0[1], S0a, 0, 0, 0);
      S0b = __builtin_amdgcn_mfma_f32_16x16x32_f16(qfh[3], ke0[3], S0b, 0, 0, 0);
      S1a = __builtin_amdgcn_mfma_f32_16x16x32_f16(qfh[1], ke1[1], S1a, 0, 0, 0);
      S1b = __builtin_amdgcn_mfma_f32_16x16x32_f16(qfh[3], ke1[3], S1b, 0, 0, 0);

      const floatx4 S0 = S0a + S0b;  // ~1-ulp score reorder; smooth softmax path only
      const floatx4 S1 = S1a + S1b;

      // ---- scores & online softmax ----
      const int jA = j0 + n, jB = j0 + 16 + n;
      float sc0[4], sc1[4];
      for (int r = 0; r < 4; ++r) {
        int i = i0 + quad * 4 + r;
        sc0[r] = (jA <= i) ? (S0[r] * SCALE + biasA[r]) : NEG9;
        sc1[r] = (jB <= i) ? (S1[r] * SCALE + biasB[r]) : NEG9;
      }
      float mx[4];
      for (int r = 0; r < 4; ++r) mx[r] = fmaxf(sc0[r], sc1[r]);
      for (int d = 1; d < 16; d <<= 1)
        for (int r = 0; r < 4; ++r) mx[r] = fmaxf(mx[r], __shfl_xor(mx[r], d, 64));
      float alpha[4];
      _Float16 ph0[4], ph1[4];
      for (int r = 0; r < 4; ++r) {
        float mnew = fmaxf(m_[r], mx[r]);
        alpha[r] = __expf(m_[r] - mnew);  // -inf -> 0
        ph0[r] = (_Float16)__expf(sc0[r] - mnew);
        ph1[r] = (_Float16)__expf(sc1[r] - mnew);
        m_[r] = mnew;
      }

      // ---- P write EARLY: LDS latency overlaps the lsum tree below ----
      for (int r = 0; r < 4; ++r) {
        Ps[w][quad * 4 + r][n] = ph0[r];
        Ps[w][quad * 4 + r][n + 16] = ph1[r];
      }

      float lsum[4];
      for (int r = 0; r < 4; ++r) lsum[r] = (float)ph0[r] + (float)ph1[r];
      for (int d = 1; d < 16; d <<= 1)
        for (int r = 0; r < 4; ++r) lsum[r] += __shfl_xor(lsum[r], d, 64);
      for (int r = 0; r < 4; ++r) l_[r] = l_[r] * alpha[r] + lsum[r];
      // alpha-skip: when alpha==1 wave-wide, the rescale is an fp32 identity — skip it
      bool needResc = false;
      for (int r = 0; r < 4; ++r) needResc |= (alpha[r] != 1.0f);
      if (__any(needResc)) {
        for (int t = 0; t < 8; ++t)
          for (int r = 0; r < 4; ++r) acc[t][r] *= alpha[r];
      }

      __builtin_amdgcn_sched_barrier(0);
      __builtin_amdgcn_s_waitcnt(0xC07F);  // lgkmcnt(0) only
      __builtin_amdgcn_sched_barrier(0);
      half8 pf = *(half8*)&Ps[w][n][quad * 8];

      // ---- P @ V (V already in registers) ----
#pragma unroll
      for (int t = 0; t < 8; ++t)
        acc[t] = __builtin_amdgcn_mfma_f32_16x16x32_f16(pf, vf[t], acc[t], 0, 0, 0);
    }
  }

  // ---- block-level merge of 4 waves ----
  if (n == 0) {
    for (int r = 0; r < 4; ++r) {
      mW[w][quad * 4 + r] = m_[r];
      lW[w][quad * 4 + r] = l_[r];
    }
  }
  for (int t = 0; t < 8; ++t)
    for (int r = 0; r < 4; ++r) Obuf[w][quad * 4 + r][t * 16 + n] = acc[t][r];
  __syncthreads();

  if (tid < 16) {
    int r = tid;
    float M = fmaxf(fmaxf(mW[0][r], mW[1][r]), fmaxf(mW[2][r], mW[3][r]));
    float L = 0.f;
    for (int s = 0; s < 4; ++s) {
      float es = (M == -INFINITY) ? 0.0f : expf(mW[s][r] - M);
      esW[s][r] = es;
      L += lW[s][r] * es;
    }
    Mrow[r] = M;
    Lrow[r] = L;
  }
  __syncthreads();

  if (ns == 1) {
    // whole tile in this block: finalize directly
    if (tid < 16) {
      int dead = (Mrow[tid] < ALIVE_MIN) ? 1 : 0;
      deadS[tid] = dead;
      LinvS[tid] = dead ? 0.0f : 1.0f / Lrow[tid];
    }
    if (tid >= 128 && tid < 256) {
      int d = tid - 128;
      float s = 0.f;
      for (int pt = 0; pt < NVP; ++pt) s += Vpart[(h * NVP + pt) * 128 + d];
      VsS[d] = s;
    }
    __syncthreads();
    for (int idx = tid; idx < 16 * 128; idx += 256) {
      int r = idx >> 7, d = idx & 127;
      float o;
      if (deadS[r]) {
        o = VsS[d] * 0.000244140625f;  // exact uniform softmax over 4096
      } else {
        o = (Obuf[0][r][d] * esW[0][r] + Obuf[1][r][d] * esW[1][r] +
             Obuf[2][r][d] * esW[2][r] + Obuf[3][r][d] * esW[3][r]) * LinvS[r];
      }
      out[(size_t)((h * T_SEQ) + i0 + r) * HD + d] = o;
    }
    return;
  }

  // ---- write partial (m, l fp32; O fp16); separate reduce kernel merges ----
  const size_t pbase = (size_t)(h * NPART_H + p);
  if (tid < 16) {
    Pm[pbase * 16 + tid] = Mrow[tid];
    Pl[pbase * 16 + tid] = Lrow[tid];
  }
  for (int idx = tid; idx < 16 * 128; idx += 256) {
    int r = idx >> 7, d = idx & 127;
    float o = Obuf[0][r][d] * esW[0][r] + Obuf[1][r][d] * esW[1][r] +
              Obuf[2][r][d] * esW[2][r] + Obuf[3][r][d] * esW[3][r];
    Po[pbase * 2048 + idx] = (_Float16)o;
  }
}

// ---------------- Reduce: merge ns partials per tile (rt >= 32 only) ----------------
__global__ __launch_bounds__(256) void reduce2_kernel(const float* __restrict__ Pm,
                                                      const float* __restrict__ Pl,
                                                      const _Float16* __restrict__ Po,
                                                      const float* __restrict__ Vpart,
                                                      float* __restrict__ out) {
  const int rt = 32 + (int)blockIdx.x, h = blockIdx.y;
  const int a = rt >> 5;
  const int ns = a + 1;
  const int base0 = 16 * a * (a + 1) + (rt & 31) * ns;
  const int tid = threadIdx.x;

  __shared__ float esP[8][16], LinvS[16], VsS[128];
  __shared__ int deadS[16];

  if (tid < 16) {
    int r = tid;
    float m[8], M = -INFINITY;
    for (int s = 0; s < ns; ++s) {
      m[s] = Pm[(size_t)(h * NPART_H + base0 + s) * 16 + r];
      M = fmaxf(M, m[s]);
    }
    int dead = (M < ALIVE_MIN) ? 1 : 0;
    deadS[r] = dead;
    float L = 0.f;
    for (int s = 0; s < ns; ++s) {
      float es = (dead || m[s] == -INFINITY) ? 0.0f : expf(m[s] - M);
      esP[s][r] = es;
      L += Pl[(size_t)(h * NPART_H + base0 + s) * 16 + r] * es;
    }
    LinvS[r] = dead ? 0.0f : 1.0f / L;
  }
  if (tid >= 128 && tid < 256) {
    int d = tid - 128;
    float s = 0.f;
    for (int pt = 0; pt < NVP; ++pt) s += Vpart[(h * NVP + pt) * 128 + d];
    VsS[d] = s;
  }
  __syncthreads();

  for (int idx = tid; idx < 16 * 128; idx += 256) {
    int r = idx >> 7, d = idx & 127;
    float o;
    if (deadS[r]) {
      o = VsS[d] * 0.000244140625f;
    } else {
      o = 0.f;
      for (int s = 0; s < ns; ++s)
        o += (float)Po[(size_t)(h * NPART_H + base0 + s) * 2048 + idx] * esP[s][r];
      o *= LinvS[r];
    }
    out[(size_t)((h * T_SEQ) + rt * 16 + r) * HD + d] = o;
  }
}

extern "C" void kernel_launch(void* const* d_in, const int* in_sizes, int n_in,
                              void* d_out, int out_size, void* d_ws, size_t ws_size,
                              hipStream_t stream) {
  const float* Q = (const float*)d_in[0];
  const float* K = (const float*)d_in[1];
  const float* V = (const float*)d_in[2];
  const float* U = (const float*)d_in[3];
  float* out = (float*)d_out;

  char* wsb = (char*)d_ws;
  float* sds = (float*)wsb;                        // 4 MB
  float* thrG = (float*)(wsb + 4194304);           // 8 KB
  float* bmax16 = (float*)(wsb + 4202496);         // 512 KB
  float* Vpart = (float*)(wsb + 4726784);          // 64 KB (32 parts x 4 heads x 128)
  _Float16* Kh = (_Float16*)(wsb + 4792320);       // 4 MB
  _Float16* Ke = Kh + 2097152;                     // 4 MB
  _Float16* Vt = Ke + 2097152;                     // 4 MB
  float* Pm = (float*)(wsb + 17375232);            // 288 KB
  float* Pl = (float*)(wsb + 17670144);            // 288 KB
  _Float16* Po = (_Float16*)(wsb + 17965056);      // 18.9 MB -> total ~35.2 MB

  prepsds_kernel<<<7296, 256, 0, stream>>>(Q, K, V, Kh, Ke, Vt, Vpart, sds);
  bmaxthr_kernel<<<dim3(NRT, NH), 256, 0, stream>>>(sds, U, thrG, bmax16);
  attn16_kernel<<<dim3(NPART_H, NH), 256, 0, stream>>>(Q, Kh, Ke, Vt, U, sds, thrG,
                                                       bmax16, Pm, Pl, Po, Vpart, out);
  reduce2_kernel<<<dim3(NRT - 32, NH), 256, 0, stream>>>(Pm, Pl, Po, Vpart, out);
}